// Round 1
// 4705.362 us; speedup vs baseline: 1.8345x; 1.8345x over previous
//
#include <hip/hip_runtime.h>
#include <math.h>

#define B_ 32
#define T_ 512
#define U_ 64
#define V_ 32000
#define H_ 512
#define E_ 512

// ---------------- embedding gather: embedded[b,u,:] = emb_table[tok[b,u]] ----------------
__global__ void embed_kernel(const int* __restrict__ tok, const float* __restrict__ table,
                             float* __restrict__ out) {
  int row = blockIdx.x;                    // b*U + u
  int t = tok[row];
  const float4* src = (const float4*)(table + (size_t)t * H_);
  float4* dst = (float4*)(out + (size_t)row * H_);
  dst[threadIdx.x] = src[threadIdx.x];     // 128 threads * 4 floats = 512
}

__global__ void zero_kernel(float* p, int n) {
  int i = blockIdx.x * blockDim.x + threadIdx.x;
  if (i < n) p[i] = 0.f;
}

// ---------------- fp32 GEMM: C[m,n] = sum_k A[m*lda+k]*Bm[n*ldb+k] + bias[n] ----------------
// 128x128 tile, BK=8, 256 threads, 8x8 per thread. C row stride = N.
__global__ __launch_bounds__(256) void gemm_abt(
    const float* __restrict__ A, const float* __restrict__ Bm,
    const float* __restrict__ bias, float* __restrict__ C,
    int N, int K, int lda, int ldb) {
  __shared__ float As[8][128];
  __shared__ float Bs[8][128];
  int tid = threadIdx.x;
  int n0 = blockIdx.x * 128, m0 = blockIdx.y * 128;
  int lr = tid >> 1;            // 0..127: tile row being loaded
  int lk = (tid & 1) * 4;       // k sub-offset 0 or 4
  const float* Ap = A + (size_t)(m0 + lr) * lda + lk;
  const float* Bp = Bm + (size_t)(n0 + lr) * ldb + lk;
  int tx = tid & 15, ty = tid >> 4;
  float acc[8][8];
#pragma unroll
  for (int i = 0; i < 8; i++)
#pragma unroll
    for (int j = 0; j < 8; j++) acc[i][j] = 0.f;

  for (int k0 = 0; k0 < K; k0 += 8) {
    float4 av = *(const float4*)(Ap + k0);
    float4 bv = *(const float4*)(Bp + k0);
    __syncthreads();
    As[lk + 0][lr] = av.x; As[lk + 1][lr] = av.y; As[lk + 2][lr] = av.z; As[lk + 3][lr] = av.w;
    Bs[lk + 0][lr] = bv.x; Bs[lk + 1][lr] = bv.y; Bs[lk + 2][lr] = bv.z; Bs[lk + 3][lr] = bv.w;
    __syncthreads();
#pragma unroll
    for (int kk = 0; kk < 8; kk++) {
      float a[8], b[8];
      *(float4*)&a[0] = *(const float4*)&As[kk][ty * 4];
      *(float4*)&a[4] = *(const float4*)&As[kk][ty * 4 + 64];
      *(float4*)&b[0] = *(const float4*)&Bs[kk][tx * 4];
      *(float4*)&b[4] = *(const float4*)&Bs[kk][tx * 4 + 64];
#pragma unroll
      for (int i = 0; i < 8; i++)
#pragma unroll
        for (int j = 0; j < 8; j++) acc[i][j] = fmaf(a[i], b[j], acc[i][j]);
    }
  }
  float bb[8] = {0, 0, 0, 0, 0, 0, 0, 0};
  if (bias) {
    *(float4*)&bb[0] = *(const float4*)&bias[n0 + tx * 4];
    *(float4*)&bb[4] = *(const float4*)&bias[n0 + tx * 4 + 64];
  }
#pragma unroll
  for (int i = 0; i < 8; i++) {
    int m = m0 + ty * 4 + (i & 3) + (i >> 2) * 64;
    float* Crow = C + (size_t)m * N + n0;
    float4 o0 = make_float4(acc[i][0] + bb[0], acc[i][1] + bb[1], acc[i][2] + bb[2], acc[i][3] + bb[3]);
    float4 o1 = make_float4(acc[i][4] + bb[4], acc[i][5] + bb[5], acc[i][6] + bb[6], acc[i][7] + bb[7]);
    *(float4*)(Crow + tx * 4) = o0;
    *(float4*)(Crow + tx * 4 + 64) = o1;
  }
}

// ---------------- attention scores: sc_raw[b,t] = enc_proj[b,t,:].q[b]  (-inf padded) ----------------
// grid (8, 32): block (s,b) handles t in [s*64, s*64+64). 512 threads = 8 waves, wave-per-t x8.
__global__ __launch_bounds__(512) void attn_scores(
    const float* __restrict__ enc_proj, const int* __restrict__ lens,
    const float* __restrict__ embedded, const float* __restrict__ h1_prev,
    float* __restrict__ sc_raw, int u) {
  int s = blockIdx.x, b = blockIdx.y;
  int tid = threadIdx.x;
  __shared__ __align__(16) float q[H_];
  q[tid] = (u == 0) ? embedded[((size_t)b * U_ + u) * H_ + tid] : h1_prev[b * H_ + tid];
  __syncthreads();
  int len = lens[b];
  int w = tid >> 6, l = tid & 63;
  int t0 = s * 64 + w * 8;
  const float4* q4 = (const float4*)q;
  float4 b0 = q4[l], b1 = q4[l + 64];
#pragma unroll
  for (int i = 0; i < 8; i++) {
    int t = t0 + i;
    if (t < len) {
      const float4* r4 = (const float4*)(enc_proj + ((size_t)b * T_ + t) * H_);
      float4 a0 = r4[l], a1 = r4[l + 64];
      float acc = a0.x * b0.x + a0.y * b0.y + a0.z * b0.z + a0.w * b0.w
                + a1.x * b1.x + a1.y * b1.y + a1.z * b1.z + a1.w * b1.w;
#pragma unroll
      for (int off = 32; off > 0; off >>= 1) acc += __shfl_xor(acc, off, 64);
      if (l == 0) sc_raw[b * T_ + t] = acc;
    } else {
      if (l == 0) sc_raw[b * T_ + t] = -INFINITY;
    }
  }
}

// ---------------- attention context: softmax(sc_raw[b,:]) . enc_out[b,:,:] -> X[:,512+e] ----------------
// grid (8, 32): block (s,b) recomputes softmax (cheap, 2KB) and produces e-slice [s*64, s*64+64).
__global__ __launch_bounds__(512) void attn_ctx(
    const float* __restrict__ enc_out, const float* __restrict__ sc_raw,
    float* __restrict__ X, int u) {
  int s = blockIdx.x, b = blockIdx.y;
  int tid = threadIdx.x;
  __shared__ float p[T_];
  __shared__ float red[512];
  float v = sc_raw[b * T_ + tid];
  red[tid] = v;
  __syncthreads();
  for (int st = 256; st > 0; st >>= 1) { if (tid < st) red[tid] = fmaxf(red[tid], red[tid + st]); __syncthreads(); }
  float mx = red[0];
  __syncthreads();
  float e = expf(v - mx);                     // -inf -> 0
  red[tid] = e;
  __syncthreads();
  for (int st = 256; st > 0; st >>= 1) { if (tid < st) red[tid] += red[tid + st]; __syncthreads(); }
  float inv = 1.f / red[0];
  __syncthreads();
  p[tid] = e * inv;
  __syncthreads();
  int l = tid & 63, stripe = tid >> 6;        // 8 t-stripes x 64 e-columns
  const float* eo = enc_out + (size_t)b * T_ * E_ + s * 64 + l;
  float a0 = 0, a1 = 0, a2 = 0, a3 = 0, a4 = 0, a5 = 0, a6 = 0, a7 = 0;
  for (int t = stripe; t < T_; t += 64) {     // 8 independent loads in flight per thread
    a0 += p[t]      * eo[(size_t)(t)      * E_];
    a1 += p[t +  8] * eo[(size_t)(t +  8) * E_];
    a2 += p[t + 16] * eo[(size_t)(t + 16) * E_];
    a3 += p[t + 24] * eo[(size_t)(t + 24) * E_];
    a4 += p[t + 32] * eo[(size_t)(t + 32) * E_];
    a5 += p[t + 40] * eo[(size_t)(t + 40) * E_];
    a6 += p[t + 48] * eo[(size_t)(t + 48) * E_];
    a7 += p[t + 56] * eo[(size_t)(t + 56) * E_];
  }
  red[tid] = a0 + a1 + a2 + a3 + a4 + a5 + a6 + a7;
  __syncthreads();
  if (tid < 64) {
    float r = red[tid];
#pragma unroll
    for (int i = 1; i < 8; i++) r += red[tid + 64 * i];
    X[((size_t)b * U_ + u) * (H_ + E_) + H_ + s * 64 + tid] = r;
  }
}

// ---------------- GRU layer 0 (ctx half only; emb half precomputed in GI0) ----------------
// gates[b,j] = GI0[b,u,gate*512+j] + W_ihc[gate].ctx + b_ih ; h-part via W_hh.
__global__ __launch_bounds__(256) void gru0_step(
    const float* __restrict__ X, const float* __restrict__ GI0,
    const float* __restrict__ h_prev, const float* __restrict__ W_ih,
    const float* __restrict__ W_hh, const float* __restrict__ b_ih,
    const float* __restrict__ b_hh, float* __restrict__ h_next, int u) {
  int j = blockIdx.x;            // output unit 0..511
  int tid = threadIdx.x;
  __shared__ __align__(16) float Wr[512], Wz[512], Wn[512], Vr[512], Vz[512], Vn[512];
  __shared__ float red[4][256];
  {
    int h2 = tid & 127;
    const float4* wr4 = (const float4*)(W_ih + (size_t)j * 1024 + 512);
    const float4* wz4 = (const float4*)(W_ih + ((size_t)j + 512) * 1024 + 512);
    const float4* wn4 = (const float4*)(W_ih + ((size_t)j + 1024) * 1024 + 512);
    const float4* vr4 = (const float4*)(W_hh + (size_t)j * 512);
    const float4* vz4 = (const float4*)(W_hh + ((size_t)j + 512) * 512);
    const float4* vn4 = (const float4*)(W_hh + ((size_t)j + 1024) * 512);
    if (tid < 128) {
      ((float4*)Wr)[h2] = wr4[h2];
      ((float4*)Wn)[h2] = wn4[h2];
      ((float4*)Vz)[h2] = vz4[h2];
    } else {
      ((float4*)Wz)[h2] = wz4[h2];
      ((float4*)Vr)[h2] = vr4[h2];
      ((float4*)Vn)[h2] = vn4[h2];
    }
  }
  __syncthreads();
  int b = tid >> 3, s = tid & 7;
  // k = 4*(s + 8*i): 8 lanes cover a contiguous 128B span (coalesced global, bank-conflict-free LDS)
  const float4* xc = (const float4*)(X + ((size_t)b * U_ + u) * (H_ + E_) + H_);
  const float4* hp = (const float4*)(h_prev + (size_t)b * H_);
  float ar = 0, az = 0, ain = 0, ahn = 0;
#pragma unroll 4
  for (int i = 0; i < 16; i++) {
    int k4 = s + i * 8;
    float4 xv = xc[k4];
    float4 hv = hp[k4];
    float4 wr = ((const float4*)Wr)[k4];
    float4 wz = ((const float4*)Wz)[k4];
    float4 wn = ((const float4*)Wn)[k4];
    float4 vr = ((const float4*)Vr)[k4];
    float4 vz = ((const float4*)Vz)[k4];
    float4 vn = ((const float4*)Vn)[k4];
    ar += wr.x * xv.x + wr.y * xv.y + wr.z * xv.z + wr.w * xv.w
        + vr.x * hv.x + vr.y * hv.y + vr.z * hv.z + vr.w * hv.w;
    az += wz.x * xv.x + wz.y * xv.y + wz.z * xv.z + wz.w * xv.w
        + vz.x * hv.x + vz.y * hv.y + vz.z * hv.z + vz.w * hv.w;
    ain += wn.x * xv.x + wn.y * xv.y + wn.z * xv.z + wn.w * xv.w;
    ahn += vn.x * hv.x + vn.y * hv.y + vn.z * hv.z + vn.w * hv.w;
  }
  red[0][tid] = ar; red[1][tid] = az; red[2][tid] = ain; red[3][tid] = ahn;
  __syncthreads();
  if (tid < 32) {
    int bb = tid;
    float r = 0, z = 0, in_ = 0, hn = 0;
#pragma unroll
    for (int q2 = 0; q2 < 8; q2++) {
      r += red[0][bb * 8 + q2]; z += red[1][bb * 8 + q2];
      in_ += red[2][bb * 8 + q2]; hn += red[3][bb * 8 + q2];
    }
    size_t grow = ((size_t)bb * U_ + u) * 1536;
    r += GI0[grow + j] + b_ih[j] + b_hh[j];
    z += GI0[grow + 512 + j] + b_ih[512 + j] + b_hh[512 + j];
    in_ += GI0[grow + 1024 + j];
    float rg = 1.f / (1.f + expf(-r));
    float zg = 1.f / (1.f + expf(-z));
    float n = tanhf(in_ + b_ih[1024 + j] + rg * (hn + b_hh[1024 + j]));
    h_next[bb * H_ + j] = (1.f - zg) * n + zg * h_prev[bb * H_ + j];
  }
}

// ---------------- GRU layer 1: x = h0_next (K=512); also writes X[:,0:512] ----------------
__global__ __launch_bounds__(256) void gru1_step(
    const float* __restrict__ xin, const float* __restrict__ h_prev,
    const float* __restrict__ W_ih, const float* __restrict__ W_hh,
    const float* __restrict__ b_ih, const float* __restrict__ b_hh,
    float* __restrict__ h_next, float* __restrict__ X, int u) {
  int j = blockIdx.x;
  int tid = threadIdx.x;
  __shared__ __align__(16) float Wr[512], Wz[512], Wn[512], Vr[512], Vz[512], Vn[512];
  __shared__ float red[4][256];
  {
    int h2 = tid & 127;
    const float4* wr4 = (const float4*)(W_ih + (size_t)j * 512);
    const float4* wz4 = (const float4*)(W_ih + ((size_t)j + 512) * 512);
    const float4* wn4 = (const float4*)(W_ih + ((size_t)j + 1024) * 512);
    const float4* vr4 = (const float4*)(W_hh + (size_t)j * 512);
    const float4* vz4 = (const float4*)(W_hh + ((size_t)j + 512) * 512);
    const float4* vn4 = (const float4*)(W_hh + ((size_t)j + 1024) * 512);
    if (tid < 128) {
      ((float4*)Wr)[h2] = wr4[h2];
      ((float4*)Wn)[h2] = wn4[h2];
      ((float4*)Vz)[h2] = vz4[h2];
    } else {
      ((float4*)Wz)[h2] = wz4[h2];
      ((float4*)Vr)[h2] = vr4[h2];
      ((float4*)Vn)[h2] = vn4[h2];
    }
  }
  __syncthreads();
  int b = tid >> 3, s = tid & 7;
  const float4* xp = (const float4*)(xin + (size_t)b * H_);
  const float4* hp = (const float4*)(h_prev + (size_t)b * H_);
  float ar = 0, az = 0, ain = 0, ahn = 0;
#pragma unroll 4
  for (int i = 0; i < 16; i++) {
    int k4 = s + i * 8;
    float4 xv = xp[k4];
    float4 hv = hp[k4];
    float4 wr = ((const float4*)Wr)[k4];
    float4 wz = ((const float4*)Wz)[k4];
    float4 wn = ((const float4*)Wn)[k4];
    float4 vr = ((const float4*)Vr)[k4];
    float4 vz = ((const float4*)Vz)[k4];
    float4 vn = ((const float4*)Vn)[k4];
    ar += wr.x * xv.x + wr.y * xv.y + wr.z * xv.z + wr.w * xv.w
        + vr.x * hv.x + vr.y * hv.y + vr.z * hv.z + vr.w * hv.w;
    az += wz.x * xv.x + wz.y * xv.y + wz.z * xv.z + wz.w * xv.w
        + vz.x * hv.x + vz.y * hv.y + vz.z * hv.z + vz.w * hv.w;
    ain += wn.x * xv.x + wn.y * xv.y + wn.z * xv.z + wn.w * xv.w;
    ahn += vn.x * hv.x + vn.y * hv.y + vn.z * hv.z + vn.w * hv.w;
  }
  red[0][tid] = ar; red[1][tid] = az; red[2][tid] = ain; red[3][tid] = ahn;
  __syncthreads();
  if (tid < 32) {
    int bb = tid;
    float r = 0, z = 0, in_ = 0, hn = 0;
#pragma unroll
    for (int q2 = 0; q2 < 8; q2++) {
      r += red[0][bb * 8 + q2]; z += red[1][bb * 8 + q2];
      in_ += red[2][bb * 8 + q2]; hn += red[3][bb * 8 + q2];
    }
    r += b_ih[j] + b_hh[j];
    z += b_ih[512 + j] + b_hh[512 + j];
    float rg = 1.f / (1.f + expf(-r));
    float zg = 1.f / (1.f + expf(-z));
    float n = tanhf(in_ + b_ih[1024 + j] + rg * (hn + b_hh[1024 + j]));
    float ho = (1.f - zg) * n + zg * h_prev[bb * H_ + j];
    h_next[bb * H_ + j] = ho;
    X[((size_t)bb * U_ + u) * (H_ + E_) + j] = ho;
  }
}

extern "C" void kernel_launch(void* const* d_in, const int* in_sizes, int n_in,
                              void* d_out, int out_size, void* d_ws, size_t ws_size,
                              hipStream_t stream) {
  const float* encoder_out  = (const float*)d_in[0];
  const int*   encoder_lens = (const int*)d_in[1];
  const int*   decoder_in   = (const int*)d_in[2];
  const float* emb_table    = (const float*)d_in[3];
  const float* W_attn       = (const float*)d_in[4];
  const float* W_ih0        = (const float*)d_in[5];
  const float* W_hh0        = (const float*)d_in[6];
  const float* b_ih0        = (const float*)d_in[7];
  const float* b_hh0        = (const float*)d_in[8];
  const float* W_ih1        = (const float*)d_in[9];
  const float* W_hh1        = (const float*)d_in[10];
  const float* b_ih1        = (const float*)d_in[11];
  const float* b_hh1        = (const float*)d_in[12];
  const float* W_out        = (const float*)d_in[13];
  const float* b_out        = (const float*)d_in[14];
  float* out = (float*)d_out;

  // ws: X [2048x1024] + h0 ping-pong [2x32x512] + h1 ping-pong [2x32x512]
  float* X   = (float*)d_ws;
  float* h0b = X + 2097152;
  float* h1b = h0b + 32768;
  // big loop-invariant temps live in the head of d_out (fully overwritten by final GEMM)
  float* enc_proj = out;                    //  8,388,608 floats
  float* embedded = out + 8388608;          //  1,048,576 floats
  float* GI0      = out + 9437184;          //  3,145,728 floats (emb-part gates, all steps)
  float* sc_raw   = out + 12582912;         //     16,384 floats (per-step scores)

  // init hidden states (both ping-pong buffers, contiguous 65536 floats)
  zero_kernel<<<256, 256, 0, stream>>>(h0b, 65536);
  embed_kernel<<<B_ * U_, 128, 0, stream>>>(decoder_in, emb_table, embedded);
  // enc_proj[b,t,h] = sum_e encoder_out[b,t,e] * W_attn[h,e]  (M=16384, N=512, K=512)
  gemm_abt<<<dim3(4, 128), 256, 0, stream>>>(encoder_out, W_attn, nullptr, enc_proj, 512, 512, 512, 512);
  // GI0[b,u,g*512+j] = embedded[b,u,:] . W_ih0[g*512+j, 0:512]  (M=2048, N=1536, K=512, ldb=1024)
  gemm_abt<<<dim3(12, 16), 256, 0, stream>>>(embedded, W_ih0, nullptr, GI0, 1536, 512, 512, 1024);

  for (int u = 0; u < U_; u++) {
    int cur = u & 1, nxt = cur ^ 1;
    attn_scores<<<dim3(8, B_), 512, 0, stream>>>(enc_proj, encoder_lens, embedded,
                                                 h1b + cur * 16384, sc_raw, u);
    attn_ctx<<<dim3(8, B_), 512, 0, stream>>>(encoder_out, sc_raw, X, u);
    gru0_step<<<512, 256, 0, stream>>>(X, GI0, h0b + cur * 16384, W_ih0, W_hh0,
                                       b_ih0, b_hh0, h0b + nxt * 16384, u);
    gru1_step<<<512, 256, 0, stream>>>(h0b + nxt * 16384, h1b + cur * 16384, W_ih1, W_hh1,
                                       b_ih1, b_hh1, h1b + nxt * 16384, X, u);
  }
  // logits: out[(b*U+u)*V + v] = X[row,:] . W_out[v,:] + b_out[v]  (M=2048, N=32000, K=1024)
  gemm_abt<<<dim3(250, 16), 256, 0, stream>>>(X, W_out, b_out, out, V_, 1024, 1024, 1024);
}

// Round 2
// 3863.575 us; speedup vs baseline: 2.2342x; 1.2179x over previous
//
#include <hip/hip_runtime.h>
#include <math.h>

#define B_ 32
#define T_ 512
#define U_ 64
#define V_ 32000
#define H_ 512
#define E_ 512

typedef short short8 __attribute__((ext_vector_type(8)));
typedef float f32x4 __attribute__((ext_vector_type(4)));

// ---------------- embedding gather: embedded[b,u,:] = emb_table[tok[b,u]] ----------------
__global__ void embed_kernel(const int* __restrict__ tok, const float* __restrict__ table,
                             float* __restrict__ out) {
  int row = blockIdx.x;                    // b*U + u
  int t = tok[row];
  const float4* src = (const float4*)(table + (size_t)t * H_);
  float4* dst = (float4*)(out + (size_t)row * H_);
  dst[threadIdx.x] = src[threadIdx.x];     // 128 threads * 4 floats = 512
}

__global__ void zero_kernel(float* p, int n) {
  int i = blockIdx.x * blockDim.x + threadIdx.x;
  if (i < n) p[i] = 0.f;
}

// ---------------- split-bf16 pack: p = (hi bits) | (bf16(f - hi) >> 16) ----------------
__device__ __forceinline__ unsigned pack1(float f) {
  unsigned u = __float_as_uint(f);
  unsigned hi = u & 0xffff0000u;
  float lo = f - __uint_as_float(hi);      // exact
  return hi | (__float_as_uint(lo) >> 16);
}

__global__ __launch_bounds__(256) void pack_kernel(const float4* __restrict__ src,
                                                   uint4* __restrict__ dst, int n4) {
  int i = blockIdx.x * blockDim.x + threadIdx.x;
  if (i < n4) {
    float4 f = src[i];
    uint4 o;
    o.x = pack1(f.x); o.y = pack1(f.y); o.z = pack1(f.z); o.w = pack1(f.w);
    dst[i] = o;
  }
}

// ---------------- fp32 GEMM: C[m,n] = sum_k A[m*lda+k]*Bm[n*ldb+k] + bias[n] ----------------
// 128x128 tile, BK=8, 256 threads, 8x8 per thread. C row stride = N.
__global__ __launch_bounds__(256) void gemm_abt(
    const float* __restrict__ A, const float* __restrict__ Bm,
    const float* __restrict__ bias, float* __restrict__ C,
    int N, int K, int lda, int ldb) {
  __shared__ float As[8][128];
  __shared__ float Bs[8][128];
  int tid = threadIdx.x;
  int n0 = blockIdx.x * 128, m0 = blockIdx.y * 128;
  int lr = tid >> 1;            // 0..127: tile row being loaded
  int lk = (tid & 1) * 4;       // k sub-offset 0 or 4
  const float* Ap = A + (size_t)(m0 + lr) * lda + lk;
  const float* Bp = Bm + (size_t)(n0 + lr) * ldb + lk;
  int tx = tid & 15, ty = tid >> 4;
  float acc[8][8];
#pragma unroll
  for (int i = 0; i < 8; i++)
#pragma unroll
    for (int j = 0; j < 8; j++) acc[i][j] = 0.f;

  for (int k0 = 0; k0 < K; k0 += 8) {
    float4 av = *(const float4*)(Ap + k0);
    float4 bv = *(const float4*)(Bp + k0);
    __syncthreads();
    As[lk + 0][lr] = av.x; As[lk + 1][lr] = av.y; As[lk + 2][lr] = av.z; As[lk + 3][lr] = av.w;
    Bs[lk + 0][lr] = bv.x; Bs[lk + 1][lr] = bv.y; Bs[lk + 2][lr] = bv.z; Bs[lk + 3][lr] = bv.w;
    __syncthreads();
#pragma unroll
    for (int kk = 0; kk < 8; kk++) {
      float a[8], b[8];
      *(float4*)&a[0] = *(const float4*)&As[kk][ty * 4];
      *(float4*)&a[4] = *(const float4*)&As[kk][ty * 4 + 64];
      *(float4*)&b[0] = *(const float4*)&Bs[kk][tx * 4];
      *(float4*)&b[4] = *(const float4*)&Bs[kk][tx * 4 + 64];
#pragma unroll
      for (int i = 0; i < 8; i++)
#pragma unroll
        for (int j = 0; j < 8; j++) acc[i][j] = fmaf(a[i], b[j], acc[i][j]);
    }
  }
  float bb[8] = {0, 0, 0, 0, 0, 0, 0, 0};
  if (bias) {
    *(float4*)&bb[0] = *(const float4*)&bias[n0 + tx * 4];
    *(float4*)&bb[4] = *(const float4*)&bias[n0 + tx * 4 + 64];
  }
#pragma unroll
  for (int i = 0; i < 8; i++) {
    int m = m0 + ty * 4 + (i & 3) + (i >> 2) * 64;
    float* Crow = C + (size_t)m * N + n0;
    float4 o0 = make_float4(acc[i][0] + bb[0], acc[i][1] + bb[1], acc[i][2] + bb[2], acc[i][3] + bb[3]);
    float4 o1 = make_float4(acc[i][4] + bb[4], acc[i][5] + bb[5], acc[i][6] + bb[6], acc[i][7] + bb[7]);
    *(float4*)(Crow + tx * 4) = o0;
    *(float4*)(Crow + tx * 4 + 64) = o1;
  }
}

// ---------------- split-bf16 MFMA GEMM: C[m,n] = sum_k A[m,k]*B[n,k] + bias[n] ----------------
// A,B packed uint32 = (hi bf16 bits<<16 ... ) | (lo bf16>>16). 128x128 tile, BK=64, 4 waves.
// LDS tiles stored as [row][16 x 16B-blocks], block index XOR-swizzled by (row&15).
__device__ __forceinline__ void unpack8(uint4 u0, uint4 u1, short8& h, short8& l) {
  h[0] = (short)(u0.x >> 16); l[0] = (short)(u0.x & 0xffffu);
  h[1] = (short)(u0.y >> 16); l[1] = (short)(u0.y & 0xffffu);
  h[2] = (short)(u0.z >> 16); l[2] = (short)(u0.z & 0xffffu);
  h[3] = (short)(u0.w >> 16); l[3] = (short)(u0.w & 0xffffu);
  h[4] = (short)(u1.x >> 16); l[4] = (short)(u1.x & 0xffffu);
  h[5] = (short)(u1.y >> 16); l[5] = (short)(u1.y & 0xffffu);
  h[6] = (short)(u1.z >> 16); l[6] = (short)(u1.z & 0xffffu);
  h[7] = (short)(u1.w >> 16); l[7] = (short)(u1.w & 0xffffu);
}

__global__ __launch_bounds__(256) void gemm_mfma(
    const unsigned* __restrict__ Ap, const unsigned* __restrict__ Bp,
    const float* __restrict__ bias, float* __restrict__ C, int N, int K) {
  __shared__ __align__(16) unsigned As[128 * 64];
  __shared__ __align__(16) unsigned Bs[128 * 64];
  int tid = threadIdx.x;
  int n0 = blockIdx.x * 128, m0 = blockIdx.y * 128;
  int w = tid >> 6, l = tid & 63;
  int wm = (w >> 1) * 64, wn = (w & 1) * 64;
  f32x4 acc[4][4];
#pragma unroll
  for (int i = 0; i < 4; i++)
#pragma unroll
    for (int j = 0; j < 4; j++) acc[i][j] = (f32x4){0.f, 0.f, 0.f, 0.f};

  for (int kt = 0; kt < K; kt += 64) {
    __syncthreads();                      // prior reads done before overwrite
#pragma unroll
    for (int i = 0; i < 8; i++) {
      int off16 = tid + i * 256;          // dest 16B-block
      int row = off16 >> 4, c = off16 & 15;
      int sc = c ^ (row & 15);            // source k-block (involution)
      *(uint4*)&As[(size_t)off16 * 4] = *(const uint4*)&Ap[(size_t)(m0 + row) * K + kt + sc * 4];
      *(uint4*)&Bs[(size_t)off16 * 4] = *(const uint4*)&Bp[(size_t)(n0 + row) * K + kt + sc * 4];
    }
    __syncthreads();
#pragma unroll
    for (int kk = 0; kk < 2; kk++) {
      short8 ah[4], al[4], bh[4], bl[4];
      int c0 = kk * 8 + (l >> 4) * 2;     // 16B-block of this lane's first 4 k-elems
#pragma unroll
      for (int fm = 0; fm < 4; fm++) {
        int row = wm + fm * 16 + (l & 15);
        uint4 u0 = *(const uint4*)&As[(row * 16 + (c0 ^ (row & 15))) * 4];
        uint4 u1 = *(const uint4*)&As[(row * 16 + ((c0 + 1) ^ (row & 15))) * 4];
        unpack8(u0, u1, ah[fm], al[fm]);
      }
#pragma unroll
      for (int fn = 0; fn < 4; fn++) {
        int row = wn + fn * 16 + (l & 15);
        uint4 u0 = *(const uint4*)&Bs[(row * 16 + (c0 ^ (row & 15))) * 4];
        uint4 u1 = *(const uint4*)&Bs[(row * 16 + ((c0 + 1) ^ (row & 15))) * 4];
        unpack8(u0, u1, bh[fn], bl[fn]);
      }
#pragma unroll
      for (int fm = 0; fm < 4; fm++)
#pragma unroll
        for (int fn = 0; fn < 4; fn++) {
          acc[fm][fn] = __builtin_amdgcn_mfma_f32_16x16x32_bf16(ah[fm], bh[fn], acc[fm][fn], 0, 0, 0);
          acc[fm][fn] = __builtin_amdgcn_mfma_f32_16x16x32_bf16(ah[fm], bl[fn], acc[fm][fn], 0, 0, 0);
          acc[fm][fn] = __builtin_amdgcn_mfma_f32_16x16x32_bf16(al[fm], bh[fn], acc[fm][fn], 0, 0, 0);
        }
    }
  }
  // epilogue: D col = l&15 (n), row = (l>>4)*4 + r (m)   [m89/m91-verified layout]
#pragma unroll
  for (int fn = 0; fn < 4; fn++) {
    int n = n0 + wn + fn * 16 + (l & 15);
    float bz = bias ? bias[n] : 0.f;
#pragma unroll
    for (int fm = 0; fm < 4; fm++) {
      int mbase = m0 + wm + fm * 16 + (l >> 4) * 4;
#pragma unroll
      for (int r = 0; r < 4; r++) C[(size_t)(mbase + r) * N + n] = acc[fm][fn][r] + bz;
    }
  }
}

// ---------------- attention scores: sc_raw[b,t] = enc_proj[b,t,:].q[b]  (-inf padded) ----------------
__global__ __launch_bounds__(512) void attn_scores(
    const float* __restrict__ enc_proj, const int* __restrict__ lens,
    const float* __restrict__ embedded, const float* __restrict__ h1_prev,
    float* __restrict__ sc_raw, int u) {
  int s = blockIdx.x, b = blockIdx.y;
  int tid = threadIdx.x;
  __shared__ __align__(16) float q[H_];
  q[tid] = (u == 0) ? embedded[((size_t)b * U_ + u) * H_ + tid] : h1_prev[b * H_ + tid];
  __syncthreads();
  int len = lens[b];
  int w = tid >> 6, l = tid & 63;
  int t0 = s * 64 + w * 8;
  const float4* q4 = (const float4*)q;
  float4 b0 = q4[l], b1 = q4[l + 64];
#pragma unroll
  for (int i = 0; i < 8; i++) {
    int t = t0 + i;
    if (t < len) {
      const float4* r4 = (const float4*)(enc_proj + ((size_t)b * T_ + t) * H_);
      float4 a0 = r4[l], a1 = r4[l + 64];
      float acc = a0.x * b0.x + a0.y * b0.y + a0.z * b0.z + a0.w * b0.w
                + a1.x * b1.x + a1.y * b1.y + a1.z * b1.z + a1.w * b1.w;
#pragma unroll
      for (int off = 32; off > 0; off >>= 1) acc += __shfl_xor(acc, off, 64);
      if (l == 0) sc_raw[b * T_ + t] = acc;
    } else {
      if (l == 0) sc_raw[b * T_ + t] = -INFINITY;
    }
  }
}

// ---------------- attention context: softmax(sc_raw[b,:]) . enc_out[b,:,:] -> X[:,512+e] ----------------
__global__ __launch_bounds__(512) void attn_ctx(
    const float* __restrict__ enc_out, const float* __restrict__ sc_raw,
    float* __restrict__ X, int u) {
  int s = blockIdx.x, b = blockIdx.y;
  int tid = threadIdx.x;
  __shared__ float p[T_];
  __shared__ float red[512];
  float v = sc_raw[b * T_ + tid];
  red[tid] = v;
  __syncthreads();
  for (int st = 256; st > 0; st >>= 1) { if (tid < st) red[tid] = fmaxf(red[tid], red[tid + st]); __syncthreads(); }
  float mx = red[0];
  __syncthreads();
  float e = expf(v - mx);                     // -inf -> 0
  red[tid] = e;
  __syncthreads();
  for (int st = 256; st > 0; st >>= 1) { if (tid < st) red[tid] += red[tid + st]; __syncthreads(); }
  float inv = 1.f / red[0];
  __syncthreads();
  p[tid] = e * inv;
  __syncthreads();
  int l = tid & 63, stripe = tid >> 6;        // 8 t-stripes x 64 e-columns
  const float* eo = enc_out + (size_t)b * T_ * E_ + s * 64 + l;
  float a0 = 0, a1 = 0, a2 = 0, a3 = 0, a4 = 0, a5 = 0, a6 = 0, a7 = 0;
  for (int t = stripe; t < T_; t += 64) {     // 8 independent loads in flight per thread
    a0 += p[t]      * eo[(size_t)(t)      * E_];
    a1 += p[t +  8] * eo[(size_t)(t +  8) * E_];
    a2 += p[t + 16] * eo[(size_t)(t + 16) * E_];
    a3 += p[t + 24] * eo[(size_t)(t + 24) * E_];
    a4 += p[t + 32] * eo[(size_t)(t + 32) * E_];
    a5 += p[t + 40] * eo[(size_t)(t + 40) * E_];
    a6 += p[t + 48] * eo[(size_t)(t + 48) * E_];
    a7 += p[t + 56] * eo[(size_t)(t + 56) * E_];
  }
  red[tid] = a0 + a1 + a2 + a3 + a4 + a5 + a6 + a7;
  __syncthreads();
  if (tid < 64) {
    float r = red[tid];
#pragma unroll
    for (int i = 1; i < 8; i++) r += red[tid + 64 * i];
    X[((size_t)b * U_ + u) * (H_ + E_) + H_ + s * 64 + tid] = r;
  }
}

// ---------------- GRU layer 0 (ctx half only; emb half precomputed in GI0) ----------------
__global__ __launch_bounds__(256) void gru0_step(
    const float* __restrict__ X, const float* __restrict__ GI0,
    const float* __restrict__ h_prev, const float* __restrict__ W_ih,
    const float* __restrict__ W_hh, const float* __restrict__ b_ih,
    const float* __restrict__ b_hh, float* __restrict__ h_next, int u) {
  int j = blockIdx.x;            // output unit 0..511
  int tid = threadIdx.x;
  __shared__ __align__(16) float Wr[512], Wz[512], Wn[512], Vr[512], Vz[512], Vn[512];
  __shared__ float red[4][256];
  {
    int h2 = tid & 127;
    const float4* wr4 = (const float4*)(W_ih + (size_t)j * 1024 + 512);
    const float4* wz4 = (const float4*)(W_ih + ((size_t)j + 512) * 1024 + 512);
    const float4* wn4 = (const float4*)(W_ih + ((size_t)j + 1024) * 1024 + 512);
    const float4* vr4 = (const float4*)(W_hh + (size_t)j * 512);
    const float4* vz4 = (const float4*)(W_hh + ((size_t)j + 512) * 512);
    const float4* vn4 = (const float4*)(W_hh + ((size_t)j + 1024) * 512);
    if (tid < 128) {
      ((float4*)Wr)[h2] = wr4[h2];
      ((float4*)Wn)[h2] = wn4[h2];
      ((float4*)Vz)[h2] = vz4[h2];
    } else {
      ((float4*)Wz)[h2] = wz4[h2];
      ((float4*)Vr)[h2] = vr4[h2];
      ((float4*)Vn)[h2] = vn4[h2];
    }
  }
  __syncthreads();
  int b = tid >> 3, s = tid & 7;
  const float4* xc = (const float4*)(X + ((size_t)b * U_ + u) * (H_ + E_) + H_);
  const float4* hp = (const float4*)(h_prev + (size_t)b * H_);
  float ar = 0, az = 0, ain = 0, ahn = 0;
#pragma unroll 4
  for (int i = 0; i < 16; i++) {
    int k4 = s + i * 8;
    float4 xv = xc[k4];
    float4 hv = hp[k4];
    float4 wr = ((const float4*)Wr)[k4];
    float4 wz = ((const float4*)Wz)[k4];
    float4 wn = ((const float4*)Wn)[k4];
    float4 vr = ((const float4*)Vr)[k4];
    float4 vz = ((const float4*)Vz)[k4];
    float4 vn = ((const float4*)Vn)[k4];
    ar += wr.x * xv.x + wr.y * xv.y + wr.z * xv.z + wr.w * xv.w
        + vr.x * hv.x + vr.y * hv.y + vr.z * hv.z + vr.w * hv.w;
    az += wz.x * xv.x + wz.y * xv.y + wz.z * xv.z + wz.w * xv.w
        + vz.x * hv.x + vz.y * hv.y + vz.z * hv.z + vz.w * hv.w;
    ain += wn.x * xv.x + wn.y * xv.y + wn.z * xv.z + wn.w * xv.w;
    ahn += vn.x * hv.x + vn.y * hv.y + vn.z * hv.z + vn.w * hv.w;
  }
  red[0][tid] = ar; red[1][tid] = az; red[2][tid] = ain; red[3][tid] = ahn;
  __syncthreads();
  if (tid < 32) {
    int bb = tid;
    float r = 0, z = 0, in_ = 0, hn = 0;
#pragma unroll
    for (int q2 = 0; q2 < 8; q2++) {
      r += red[0][bb * 8 + q2]; z += red[1][bb * 8 + q2];
      in_ += red[2][bb * 8 + q2]; hn += red[3][bb * 8 + q2];
    }
    size_t grow = ((size_t)bb * U_ + u) * 1536;
    r += GI0[grow + j] + b_ih[j] + b_hh[j];
    z += GI0[grow + 512 + j] + b_ih[512 + j] + b_hh[512 + j];
    in_ += GI0[grow + 1024 + j];
    float rg = 1.f / (1.f + expf(-r));
    float zg = 1.f / (1.f + expf(-z));
    float n = tanhf(in_ + b_ih[1024 + j] + rg * (hn + b_hh[1024 + j]));
    h_next[bb * H_ + j] = (1.f - zg) * n + zg * h_prev[bb * H_ + j];
  }
}

// ---------------- GRU layer 1: x = h0_next (K=512); also writes X[:,0:512] ----------------
__global__ __launch_bounds__(256) void gru1_step(
    const float* __restrict__ xin, const float* __restrict__ h_prev,
    const float* __restrict__ W_ih, const float* __restrict__ W_hh,
    const float* __restrict__ b_ih, const float* __restrict__ b_hh,
    float* __restrict__ h_next, float* __restrict__ X, int u) {
  int j = blockIdx.x;
  int tid = threadIdx.x;
  __shared__ __align__(16) float Wr[512], Wz[512], Wn[512], Vr[512], Vz[512], Vn[512];
  __shared__ float red[4][256];
  {
    int h2 = tid & 127;
    const float4* wr4 = (const float4*)(W_ih + (size_t)j * 512);
    const float4* wz4 = (const float4*)(W_ih + ((size_t)j + 512) * 512);
    const float4* wn4 = (const float4*)(W_ih + ((size_t)j + 1024) * 512);
    const float4* vr4 = (const float4*)(W_hh + (size_t)j * 512);
    const float4* vz4 = (const float4*)(W_hh + ((size_t)j + 512) * 512);
    const float4* vn4 = (const float4*)(W_hh + ((size_t)j + 1024) * 512);
    if (tid < 128) {
      ((float4*)Wr)[h2] = wr4[h2];
      ((float4*)Wn)[h2] = wn4[h2];
      ((float4*)Vz)[h2] = vz4[h2];
    } else {
      ((float4*)Wz)[h2] = wz4[h2];
      ((float4*)Vr)[h2] = vr4[h2];
      ((float4*)Vn)[h2] = vn4[h2];
    }
  }
  __syncthreads();
  int b = tid >> 3, s = tid & 7;
  const float4* xp = (const float4*)(xin + (size_t)b * H_);
  const float4* hp = (const float4*)(h_prev + (size_t)b * H_);
  float ar = 0, az = 0, ain = 0, ahn = 0;
#pragma unroll 4
  for (int i = 0; i < 16; i++) {
    int k4 = s + i * 8;
    float4 xv = xp[k4];
    float4 hv = hp[k4];
    float4 wr = ((const float4*)Wr)[k4];
    float4 wz = ((const float4*)Wz)[k4];
    float4 wn = ((const float4*)Wn)[k4];
    float4 vr = ((const float4*)Vr)[k4];
    float4 vz = ((const float4*)Vz)[k4];
    float4 vn = ((const float4*)Vn)[k4];
    ar += wr.x * xv.x + wr.y * xv.y + wr.z * xv.z + wr.w * xv.w
        + vr.x * hv.x + vr.y * hv.y + vr.z * hv.z + vr.w * hv.w;
    az += wz.x * xv.x + wz.y * xv.y + wz.z * xv.z + wz.w * xv.w
        + vz.x * hv.x + vz.y * hv.y + vz.z * hv.z + vz.w * hv.w;
    ain += wn.x * xv.x + wn.y * xv.y + wn.z * xv.z + wn.w * xv.w;
    ahn += vn.x * hv.x + vn.y * hv.y + vn.z * hv.z + vn.w * hv.w;
  }
  red[0][tid] = ar; red[1][tid] = az; red[2][tid] = ain; red[3][tid] = ahn;
  __syncthreads();
  if (tid < 32) {
    int bb = tid;
    float r = 0, z = 0, in_ = 0, hn = 0;
#pragma unroll
    for (int q2 = 0; q2 < 8; q2++) {
      r += red[0][bb * 8 + q2]; z += red[1][bb * 8 + q2];
      in_ += red[2][bb * 8 + q2]; hn += red[3][bb * 8 + q2];
    }
    r += b_ih[j] + b_hh[j];
    z += b_ih[512 + j] + b_hh[512 + j];
    float rg = 1.f / (1.f + expf(-r));
    float zg = 1.f / (1.f + expf(-z));
    float n = tanhf(in_ + b_ih[1024 + j] + rg * (hn + b_hh[1024 + j]));
    float ho = (1.f - zg) * n + zg * h_prev[bb * H_ + j];
    h_next[bb * H_ + j] = ho;
    X[((size_t)bb * U_ + u) * (H_ + E_) + j] = ho;
  }
}

extern "C" void kernel_launch(void* const* d_in, const int* in_sizes, int n_in,
                              void* d_out, int out_size, void* d_ws, size_t ws_size,
                              hipStream_t stream) {
  const float* encoder_out  = (const float*)d_in[0];
  const int*   encoder_lens = (const int*)d_in[1];
  const int*   decoder_in   = (const int*)d_in[2];
  const float* emb_table    = (const float*)d_in[3];
  const float* W_attn       = (const float*)d_in[4];
  const float* W_ih0        = (const float*)d_in[5];
  const float* W_hh0        = (const float*)d_in[6];
  const float* b_ih0        = (const float*)d_in[7];
  const float* b_hh0        = (const float*)d_in[8];
  const float* W_ih1        = (const float*)d_in[9];
  const float* W_hh1        = (const float*)d_in[10];
  const float* b_ih1        = (const float*)d_in[11];
  const float* b_hh1        = (const float*)d_in[12];
  const float* W_out        = (const float*)d_in[13];
  const float* b_out        = (const float*)d_in[14];
  float* out = (float*)d_out;

  // ws: X [2048x1024] + h0/h1 ping-pong + (optional) packed X + packed W_out
  float* X   = (float*)d_ws;
  float* h0b = X + 2097152;
  float* h1b = h0b + 32768;
  unsigned* Xpack = (unsigned*)(h1b + 32768);     //  2,097,152 u32
  unsigned* Wpack = Xpack + 2097152;              // 32,768,000 u32
  size_t ws_need = ((size_t)2097152 + 65536 + 2097152 + 32768000) * 4;
  bool use_mfma = ws_size >= ws_need;

  // big loop-invariant temps live in the head of d_out (fully overwritten by final GEMM)
  float* enc_proj = out;                    //  8,388,608 floats
  float* embedded = out + 8388608;          //  1,048,576 floats
  float* GI0      = out + 9437184;          //  3,145,728 floats (emb-part gates, all steps)
  float* sc_raw   = out + 12582912;         //     16,384 floats (per-step scores)

  zero_kernel<<<256, 256, 0, stream>>>(h0b, 65536);
  embed_kernel<<<B_ * U_, 128, 0, stream>>>(decoder_in, emb_table, embedded);
  // enc_proj[b,t,h] = sum_e encoder_out[b,t,e] * W_attn[h,e]  (M=16384, N=512, K=512)
  gemm_abt<<<dim3(4, 128), 256, 0, stream>>>(encoder_out, W_attn, nullptr, enc_proj, 512, 512, 512, 512);
  // GI0[b,u,g*512+j] = embedded[b,u,:] . W_ih0[g*512+j, 0:512]  (M=2048, N=1536, K=512, ldb=1024)
  gemm_abt<<<dim3(12, 16), 256, 0, stream>>>(embedded, W_ih0, nullptr, GI0, 1536, 512, 512, 1024);
  if (use_mfma) {
    // split W_out into bf16 hi/lo pairs once (loop-invariant)
    pack_kernel<<<32000, 256, 0, stream>>>((const float4*)W_out, (uint4*)Wpack, 8192000);
  }

  for (int u = 0; u < U_; u++) {
    int cur = u & 1, nxt = cur ^ 1;
    attn_scores<<<dim3(8, B_), 512, 0, stream>>>(enc_proj, encoder_lens, embedded,
                                                 h1b + cur * 16384, sc_raw, u);
    attn_ctx<<<dim3(8, B_), 512, 0, stream>>>(encoder_out, sc_raw, X, u);
    gru0_step<<<512, 256, 0, stream>>>(X, GI0, h0b + cur * 16384, W_ih0, W_hh0,
                                       b_ih0, b_hh0, h0b + nxt * 16384, u);
    gru1_step<<<512, 256, 0, stream>>>(h0b + nxt * 16384, h1b + cur * 16384, W_ih1, W_hh1,
                                       b_ih1, b_hh1, h1b + nxt * 16384, X, u);
  }
  // logits: out[(b*U+u)*V + v] = X[row,:] . W_out[v,:] + b_out[v]  (M=2048, N=32000, K=1024)
  if (use_mfma) {
    pack_kernel<<<2048, 256, 0, stream>>>((const float4*)X, (uint4*)Xpack, 524288);
    gemm_mfma<<<dim3(250, 16), 256, 0, stream>>>(Xpack, Wpack, b_out, out, V_, 1024);
  } else {
    gemm_abt<<<dim3(250, 16), 256, 0, stream>>>(X, W_out, b_out, out, V_, 1024, 1024, 1024);
  }
}